// Round 5
// baseline (205.549 us; speedup 1.0000x reference)
//
#include <hip/hip_runtime.h>

#define NUM_ITERS 500
#define LR_F 0.001f
#define VPLANE 262144    // 4*64*1024 floats
// K=1 Krylov truncation: s = d0*v0, d0 = 500*LR/||v0||.
// R20: k_prep removed (scalar weight loads), Gam via block partials. GOOD.
//      atomicAdd epilogue BAD (33MB write amp) -> Fp + k_fsum2.
// R21: LDS pitch-skew ~NEUTRAL (bank theory falsified).
// R22: register-direct conv (no LDS/barriers) WIN: 147.7 -> 118.4 us.
// R23: attack latency-boundedness (UNMEASURED last round: broker timeout;
//      resubmitted verbatim this round).
//  - 8 px/thread (2 rows x 4 cols), grid 512 -> 1024 (rowH split): 4 blocks/CU
//    = 4 waves/SIMD (was 2). Row split leaves all buffer layouts + summation
//    orders untouched.
//  - shfl halo -> direct clamped loads (aligned float4 + 2 dwords/row): kills
//    the load->ds_bpermute->FMA serial chain and the lgkmcnt coupling with
//    s_load weight fetches. Zero DS ops in conv kernels.
//  - FP tap order per px identical (r asc, dj asc, c asc) -> absmax unchanged.

// ---- raw weight loads (wave-uniform addresses -> scalar loads) --------------
__device__ __forceinline__ void wldI(const float* __restrict__ Wff,
                                     const float* __restrict__ Wb,
                                     int oc, float w[10]) {
  const float* s = Wff + (size_t)oc * 9;
#pragma unroll
  for (int k = 0; k < 9; ++k) w[k] = s[k];
  w[9] = Wb[oc];
}
__device__ __forceinline__ void wldF(const float* __restrict__ Wfb,
                                     int ci, int och, float w[10]) {
  const float* s = Wfb + ((size_t)ci * 64 + och) * 9;
#pragma unroll
  for (int k = 0; k < 9; ++k) w[k] = s[k];
  w[9] = 0.f;
}
__device__ __forceinline__ void wldZ(const float* __restrict__ Wfb,
                                     int co, int ci, float w[10]) {
  const float* s = Wfb + ((size_t)co * 64 + ci) * 9;
#pragma unroll
  for (int k = 0; k < 9; ++k) w[k] = s[8 - k];
  w[9] = 0.f;
}

// ---- conv8_reg: 3x3 pad1 conv of one 32x32 plane, register-direct, 8 px -----
// Thread owns 2 rows (strip2, strip2+1) x 4 cols (4cg..4cg+3). Per input row r
// (image row strip2+r-1): aligned float4 + 2 clamped dwords (no shfl).
// fv[i] = image col 4cg + i - 1; output col c tap dj reads fv[c+dj].
template <bool BYP, bool SCALE>
__device__ __forceinline__ void conv8_reg(const float* __restrict__ plane,
                                          const float w[10], float d0,
                                          int strip2, int cg4, bool cg0, bool cg7,
                                          float acc[8], float by[8]) {
  float wb = w[9];
#pragma unroll
  for (int r = 0; r < 4; ++r) {
    int R = strip2 - 1 + r;
    bool ok = (R >= 0) && (R < 32);
    int Rc = R < 0 ? 0 : (R > 31 ? 31 : R);
    const float* rp = plane + Rc * 32;
    float4 f4 = *(const float4*)(rp + cg4);
    float fl = rp[cg0 ? cg4 : cg4 - 1];
    float fr = rp[cg7 ? cg4 + 3 : cg4 + 4];
    if (!ok) { f4.x = 0.f; f4.y = 0.f; f4.z = 0.f; f4.w = 0.f; fl = 0.f; fr = 0.f; }
    if (SCALE) { f4.x *= d0; f4.y *= d0; f4.z *= d0; f4.w *= d0; fl *= d0; fr *= d0; }
    fl = cg0 ? 0.f : fl;
    fr = cg7 ? 0.f : fr;
    float fv[6] = {fl, f4.x, f4.y, f4.z, f4.w, fr};
#pragma unroll
    for (int k = 0; k < 2; ++k) {
      int di = r - k;
      if (di >= 0 && di < 3) {
#pragma unroll
        for (int dj = 0; dj < 3; ++dj) {
          float wv = w[di * 3 + dj];
#pragma unroll
          for (int c = 0; c < 4; ++c)
            acc[k * 4 + c] = fmaf(fv[c + dj], wv, acc[k * 4 + c]);
        }
        if (BYP && di == 1) {
#pragma unroll
          for (int c = 0; c < 4; ++c)
            by[k * 4 + c] = fmaf(fv[c + 1], wb, by[k * 4 + c]);
        }
      }
    }
  }
}

// ---- k_init_p: partial conv3x3(x,Wff) + partial bypass over 16-ci quarter ---
// grid 1024 = rowH(1b)|b(2b)|ochQ(5b)|ciQ(2b); 4 och/block x 8 px/thr
__global__ __launch_bounds__(256, 4) void k_init_p(const float* __restrict__ x,
                                                   const float* __restrict__ Wff,
                                                   const float* __restrict__ Wb,
                                                   float* __restrict__ Q,
                                                   float* __restrict__ Bq) {
  int tid = threadIdx.x, blk = blockIdx.x;
  int ciQ = blk & 3, ochQ = (blk >> 2) & 31, b = (blk >> 7) & 3, rowH = blk >> 9;
  int wv = __builtin_amdgcn_readfirstlane(tid >> 6);
  int och = ochQ * 4 + wv;                    // 0..127
  int strip2 = ((tid >> 3) & 7) * 2 + rowH * 16;
  int cg4 = (tid & 7) * 4;
  bool cg0 = (tid & 7) == 0, cg7 = (tid & 7) == 7;
  const float* pb = x + (size_t)(b * 64 + ciQ * 16) * 1024;
  int oc0 = och * 64 + ciQ * 16;
  float wA[10], wB[10];
  float acc[8], by[8];
#pragma unroll
  for (int i = 0; i < 8; ++i) { acc[i] = 0.f; by[i] = 0.f; }
  wldI(Wff, Wb, oc0, wA);
  for (int ci = 0; ci < 16; ci += 2) {
    wldI(Wff, Wb, oc0 + ci + 1, wB);
    conv8_reg<true, false>(pb + (size_t)ci * 1024, wA, 0.f, strip2, cg4, cg0, cg7, acc, by);
    if (ci + 2 < 16) wldI(Wff, Wb, oc0 + ci + 2, wA);
    conv8_reg<true, false>(pb + (size_t)(ci + 1) * 1024, wB, 0.f, strip2, cg4, cg0, cg7, acc, by);
  }
  size_t off = (size_t)ciQ * 524288 + (size_t)(b * 128 + och) * 1024 + strip2 * 32 + cg4;
#pragma unroll
  for (int k = 0; k < 2; ++k) {
    float4 o = {acc[k * 4], acc[k * 4 + 1], acc[k * 4 + 2], acc[k * 4 + 3]};
    float4 bo = {by[k * 4], by[k * 4 + 1], by[k * 4 + 2], by[k * 4 + 3]};
    *(float4*)(Q + off + k * 32) = o;
    *(float4*)(Bq + off + k * 32) = bo;
  }
}

// ---- k_ysum: Y = relu(sum4 Q); out-base = Y + sum4 Bq ----------------------
__global__ __launch_bounds__(256) void k_ysum(const float* __restrict__ Q,
                                              const float* __restrict__ Bq,
                                              float* __restrict__ Y,
                                              float* __restrict__ out) {
  size_t i = (size_t)(blockIdx.x * 256 + threadIdx.x) * 4;
  float4 qs = {0.f, 0.f, 0.f, 0.f}, bs = {0.f, 0.f, 0.f, 0.f};
#pragma unroll
  for (int q = 0; q < 4; ++q) {
    float4 a = *(const float4*)(Q + (size_t)q * 524288 + i);
    float4 c = *(const float4*)(Bq + (size_t)q * 524288 + i);
    qs.x += a.x; qs.y += a.y; qs.z += a.z; qs.w += a.w;
    bs.x += c.x; bs.y += c.y; bs.z += c.z; bs.w += c.w;
  }
  qs.x = qs.x > 0.f ? qs.x : 0.f; qs.y = qs.y > 0.f ? qs.y : 0.f;
  qs.z = qs.z > 0.f ? qs.z : 0.f; qs.w = qs.w > 0.f ? qs.w : 0.f;
  *(float4*)(Y + i) = qs;
  float4 ob = {qs.x + bs.x, qs.y + bs.y, qs.z + bs.z, qs.w + bs.w};
  *(float4*)(out + i) = ob;
}

// ---- k_forward_p: partial conv3x3(Y, Wfb^T) over 16-ci octant --------------
// grid 1024 = rowH(1b)|b(2b)|ochQ(4b)|ciO(3b)
__global__ __launch_bounds__(256, 4) void k_forward_p(const float* __restrict__ Y,
                                                      const float* __restrict__ Wfb,
                                                      float* __restrict__ PA) {
  int tid = threadIdx.x, blk = blockIdx.x;
  int ciO = blk & 7, ochQ = (blk >> 3) & 15, b = (blk >> 7) & 3, rowH = blk >> 9;
  int wv = __builtin_amdgcn_readfirstlane(tid >> 6);
  int och = ochQ * 4 + wv;                    // 0..63
  int strip2 = ((tid >> 3) & 7) * 2 + rowH * 16;
  int cg4 = (tid & 7) * 4;
  bool cg0 = (tid & 7) == 0, cg7 = (tid & 7) == 7;
  const float* pb = Y + (size_t)(b * 128 + ciO * 16) * 1024;
  float wA[10], wB[10];
  float acc[8], dummy[8];
#pragma unroll
  for (int i = 0; i < 8; ++i) acc[i] = 0.f;
  wldF(Wfb, ciO * 16, och, wA);
  for (int ci = 0; ci < 16; ci += 2) {
    wldF(Wfb, ciO * 16 + ci + 1, och, wB);
    conv8_reg<false, false>(pb + (size_t)ci * 1024, wA, 0.f, strip2, cg4, cg0, cg7, acc, dummy);
    if (ci + 2 < 16) wldF(Wfb, ciO * 16 + ci + 2, och, wA);
    conv8_reg<false, false>(pb + (size_t)(ci + 1) * 1024, wB, 0.f, strip2, cg4, cg0, cg7, acc, dummy);
  }
  float* dst = PA + (size_t)ciO * 262144 + (size_t)(b * 64 + och) * 1024 + strip2 * 32 + cg4;
#pragma unroll
  for (int k = 0; k < 2; ++k) {
    float4 o = {acc[k * 4], acc[k * 4 + 1], acc[k * 4 + 2], acc[k * 4 + 3]};
    *(float4*)(dst + k * 32) = o;
  }
}

// ---- k_vnorm: v0 = x - sum8(PA); Gam[blk] = block partial of ||v0||^2 ------
__global__ __launch_bounds__(256) void k_vnorm(const float* __restrict__ x,
                                               const float* __restrict__ PA,
                                               float* __restrict__ v0out,
                                               float* __restrict__ Gam) {
  __shared__ float ws[4];
  int tid = threadIdx.x;
  size_t i = (size_t)(blockIdx.x * 256 + tid) * 4;
  float4 s = {0.f, 0.f, 0.f, 0.f};
#pragma unroll
  for (int o = 0; o < 8; ++o) {
    float4 q = *(const float4*)(PA + (size_t)o * 262144 + i);
    s.x += q.x; s.y += q.y; s.z += q.z; s.w += q.w;
  }
  float4 xv = *(const float4*)(x + i);
  float4 v = {xv.x - s.x, xv.y - s.y, xv.z - s.z, xv.w - s.w};
  *(float4*)(v0out + i) = v;
  float g = v.x * v.x + v.y * v.y + v.z * v.z + v.w * v.w;
#pragma unroll
  for (int d = 32; d; d >>= 1) g += __shfl_down(g, d, 64);
  if ((tid & 63) == 0) ws[tid >> 6] = g;
  __syncthreads();
  if (tid == 0) Gam[blockIdx.x] = ws[0] + ws[1] + ws[2] + ws[3];
}

// ---- k_finalize_p: partial conv3x3(d0*v0, flip(Wfb)) over 16-ci quarter ----
// grid 1024 = rowH(1b)|b(2b)|coQ(5b)|ciQ(2b). Gam[256] reduced here.
__global__ __launch_bounds__(256, 4) void k_finalize_p(const float* __restrict__ V,
                                                       const float* __restrict__ Gam,
                                                       const float* __restrict__ Wfb,
                                                       float* __restrict__ Fp) {
  __shared__ float ws[4];
  int tid = threadIdx.x, blk = blockIdx.x;
  int ciQ = blk & 3, coQ = (blk >> 2) & 31, b = (blk >> 7) & 3, rowH = blk >> 9;
  int wv = __builtin_amdgcn_readfirstlane(tid >> 6);
  int co = coQ * 4 + wv;                      // 0..127
  int strip2 = ((tid >> 3) & 7) * 2 + rowH * 16;
  int cg4 = (tid & 7) * 4;
  bool cg0 = (tid & 7) == 0, cg7 = (tid & 7) == 7;
  // reduce Gam[0..255] -> g00 (deterministic, no atomic, no pre-zero)
  float g = Gam[tid];
#pragma unroll
  for (int d = 32; d; d >>= 1) g += __shfl_down(g, d, 64);
  if ((tid & 63) == 0) ws[tid >> 6] = g;
  __syncthreads();
  float d0 = ((float)NUM_ITERS * LR_F) *
             __builtin_amdgcn_rsqf(ws[0] + ws[1] + ws[2] + ws[3]);
  const float* pb = V + (size_t)(b * 64 + ciQ * 16) * 1024;
  float wA[10], wB[10];
  float acc[8], dummy[8];
#pragma unroll
  for (int i = 0; i < 8; ++i) acc[i] = 0.f;
  wldZ(Wfb, co, ciQ * 16, wA);
  for (int ci = 0; ci < 16; ci += 2) {
    wldZ(Wfb, co, ciQ * 16 + ci + 1, wB);
    conv8_reg<false, true>(pb + (size_t)ci * 1024, wA, d0, strip2, cg4, cg0, cg7, acc, dummy);
    if (ci + 2 < 16) wldZ(Wfb, co, ciQ * 16 + ci + 2, wA);
    conv8_reg<false, true>(pb + (size_t)(ci + 1) * 1024, wB, d0, strip2, cg4, cg0, cg7, acc, dummy);
  }
  size_t off = (size_t)ciQ * 524288 + (size_t)(b * 128 + co) * 1024 + strip2 * 32 + cg4;
#pragma unroll
  for (int k = 0; k < 2; ++k) {
    float4 o = {acc[k * 4], acc[k * 4 + 1], acc[k * 4 + 2], acc[k * 4 + 3]};
    *(float4*)(Fp + off + k * 32) = o;
  }
}

// ---- k_fsum2: out += sum4 Fp (base written by k_ysum) -----------------------
__global__ __launch_bounds__(256) void k_fsum2(const float* __restrict__ Fp,
                                               float* __restrict__ out) {
  size_t i = (size_t)(blockIdx.x * 256 + threadIdx.x) * 4;
  float4 s = *(const float4*)(out + i);
#pragma unroll
  for (int q = 0; q < 4; ++q) {
    float4 p = *(const float4*)(Fp + (size_t)q * 524288 + i);
    s.x += p.x; s.y += p.y; s.z += p.z; s.w += p.w;
  }
  *(float4*)(out + i) = s;
}

// ---- launch -----------------------------------------------------------------
extern "C" void kernel_launch(void* const* d_in, const int* in_sizes, int n_in,
                              void* d_out, int out_size, void* d_ws, size_t ws_size,
                              hipStream_t stream) {
  const float* x   = (const float*)d_in[0];
  const float* Wff = (const float*)d_in[1];
  const float* Wfb = (const float*)d_in[2];
  const float* Wb  = (const float*)d_in[3];
  float* out = (float*)d_out;

  float* V    = (float*)d_ws;                  // 262144 (v0)
  float* Gam  = V + VPLANE;                    // 256 block partials
  float* PA   = Gam + 256;                     // 8 * 262144
  float* Q    = PA + (size_t)8 * 262144;       // 4 * 524288
  float* Bq   = Q + (size_t)4 * 524288;        // 4 * 524288
  float* Fp   = Bq + (size_t)4 * 524288;       // 4 * 524288
  float* Y    = Fp + (size_t)4 * 524288;       // 524288 (relu(sum Q))

  hipLaunchKernelGGL(k_init_p,     dim3(1024), dim3(256), 0, stream, x, Wff, Wb, Q, Bq);
  hipLaunchKernelGGL(k_ysum,       dim3(512),  dim3(256), 0, stream, Q, Bq, Y, out);
  hipLaunchKernelGGL(k_forward_p,  dim3(1024), dim3(256), 0, stream, Y, Wfb, PA);
  hipLaunchKernelGGL(k_vnorm,      dim3(256),  dim3(256), 0, stream, x, PA, V, Gam);
  hipLaunchKernelGGL(k_finalize_p, dim3(1024), dim3(256), 0, stream, V, Gam, Wfb, Fp);
  hipLaunchKernelGGL(k_fsum2,      dim3(512),  dim3(256), 0, stream, Fp, out);
}

// Round 6
// 114.935 us; speedup vs baseline: 1.7884x; 1.7884x over previous
//
#include <hip/hip_runtime.h>

#define NUM_ITERS 500
#define LR_F 0.001f
#define VPLANE 262144    // 4*64*1024 floats
// K=1 Krylov truncation: s = d0*v0, d0 = 500*LR/||v0||.
// R20: k_prep removed, Gam block partials GOOD; atomic epilogue BAD.
// R21: LDS pitch-skew ~NEUTRAL (bank theory falsified).
// R22: register-direct conv (no LDS/barriers) WIN: 147.7 -> 118.4.
// R23: dword-halo + 8px/thread REGRESSED 205.5: TA/L1 instruction pipe is the
//      bottleneck; halo dwords bill full lines, 8px halves row reuse.
// R24 (this round): minimize vmem instrs per useful FMA.
//  - 16 px/thread + 6-row shfl halo restored (TA-optimal, shfl rides the
//    parallel LDS pipe).
//  - och-PAIRING: 2 output channels per thread -> each loaded row + shfl
//    feeds 2 accumulators (halves vmem+shfl per och). Weights wave-uniform.
//  - ci-split 8/block (8 partials Q/Bq/Fp, 16 for PA) keeps grid 512 =
//    2 blocks/CU, 8 waves/CU. Register-direct ci-split has no per-block cost
//    (R14's LDS-era regression does not apply); +~5us elementwise traffic.
//  - FP tap order per (px,och) identical -> absmax unchanged.

// ---- raw weight loads (wave-uniform addresses -> s_load) --------------------
__device__ __forceinline__ void wldI(const float* __restrict__ Wff,
                                     const float* __restrict__ Wb,
                                     int oc, float w[10]) {
  const float* s = Wff + (size_t)oc * 9;
#pragma unroll
  for (int k = 0; k < 9; ++k) w[k] = s[k];
  w[9] = Wb[oc];
}
__device__ __forceinline__ void wldF(const float* __restrict__ Wfb,
                                     int ci, int och, float w[10]) {
  const float* s = Wfb + ((size_t)ci * 64 + och) * 9;
#pragma unroll
  for (int k = 0; k < 9; ++k) w[k] = s[k];
  w[9] = 0.f;
}
__device__ __forceinline__ void wldZ(const float* __restrict__ Wfb,
                                     int co, int ci, float w[10]) {
  const float* s = Wfb + ((size_t)co * 64 + ci) * 9;
#pragma unroll
  for (int k = 0; k < 9; ++k) w[k] = s[8 - k];
  w[9] = 0.f;
}

// ---- conv16x2: 3x3 pad1 conv of one 32x32 plane, 16 px, 2 och ---------------
// Thread owns 4 rows (strip4..+3) x 4 cols (4cg..4cg+3). Per input row r
// (image row strip4+r-1): one aligned float4 + 2 shfl for halo; the row feeds
// BOTH och accumulators. fv[i] = image col 4cg+i-1; out col c tap dj: fv[c+dj].
template <bool BYP, bool SCALE>
__device__ __forceinline__ void conv16x2(const float* __restrict__ plane,
                                         const float w0[10], const float w1[10],
                                         float d0, int strip4, int cg4,
                                         bool cg0, bool cg7,
                                         float acc0[16], float acc1[16],
                                         float by0[16], float by1[16]) {
  float wb0 = w0[9], wb1 = w1[9];
#pragma unroll
  for (int r = 0; r < 6; ++r) {
    int R = strip4 + r - 1;
    float4 f4;
    if (r == 0) {
      bool ok = R >= 0;
      f4 = *(const float4*)(plane + (ok ? R : 0) * 32 + cg4);
      f4.x = ok ? f4.x : 0.f; f4.y = ok ? f4.y : 0.f;
      f4.z = ok ? f4.z : 0.f; f4.w = ok ? f4.w : 0.f;
    } else if (r == 5) {
      bool ok = R < 32;
      f4 = *(const float4*)(plane + (ok ? R : 31) * 32 + cg4);
      f4.x = ok ? f4.x : 0.f; f4.y = ok ? f4.y : 0.f;
      f4.z = ok ? f4.z : 0.f; f4.w = ok ? f4.w : 0.f;
    } else {
      f4 = *(const float4*)(plane + R * 32 + cg4);
    }
    if (SCALE) { f4.x *= d0; f4.y *= d0; f4.z *= d0; f4.w *= d0; }
    float fl = __shfl_up(f4.w, 1, 64);     // lane-1's col 4cg+3 == our 4cg-1
    float fr = __shfl_down(f4.x, 1, 64);   // lane+1's col 4cg   == our 4cg+4
    fl = cg0 ? 0.f : fl;
    fr = cg7 ? 0.f : fr;
    float fv[6] = {fl, f4.x, f4.y, f4.z, f4.w, fr};
#pragma unroll
    for (int k = 0; k < 4; ++k) {
      int di = r - k;
      if (di >= 0 && di < 3) {
#pragma unroll
        for (int dj = 0; dj < 3; ++dj) {
          float wv0 = w0[di * 3 + dj];
          float wv1 = w1[di * 3 + dj];
#pragma unroll
          for (int c = 0; c < 4; ++c) {
            acc0[k * 4 + c] = fmaf(fv[c + dj], wv0, acc0[k * 4 + c]);
            acc1[k * 4 + c] = fmaf(fv[c + dj], wv1, acc1[k * 4 + c]);
          }
        }
        if (BYP && di == 1) {
#pragma unroll
          for (int c = 0; c < 4; ++c) {
            by0[k * 4 + c] = fmaf(fv[c + 1], wb0, by0[k * 4 + c]);
            by1[k * 4 + c] = fmaf(fv[c + 1], wb1, by1[k * 4 + c]);
          }
        }
      }
    }
  }
}

// ---- k_init_p: partial conv3x3(x,Wff) + bypass over 8-ci octant -------------
// grid 512 = b(2b)|ochP(4b)|ciO(3b); block 256 = 4 waves x 2 och/thread
__global__ __launch_bounds__(256, 2) void k_init_p(const float* __restrict__ x,
                                                   const float* __restrict__ Wff,
                                                   const float* __restrict__ Wb,
                                                   float* __restrict__ Q,
                                                   float* __restrict__ Bq) {
  int tid = threadIdx.x, blk = blockIdx.x;
  int ciO = blk & 7, ochP = (blk >> 3) & 15, b = blk >> 7;
  int wv = __builtin_amdgcn_readfirstlane(tid >> 6);
  int och0 = ochP * 8 + wv * 2;               // 0..126, pair (och0, och0+1)
  int strip4 = ((tid >> 3) & 7) * 4;
  int cg4 = (tid & 7) * 4;
  bool cg0 = (tid & 7) == 0, cg7 = (tid & 7) == 7;
  const float* pb = x + (size_t)(b * 64 + ciO * 8) * 1024;
  int oc0 = och0 * 64 + ciO * 8, oc1 = oc0 + 64;
  float wA[10], wC[10];
  float acc0[16], acc1[16], by0[16], by1[16];
#pragma unroll
  for (int i = 0; i < 16; ++i) { acc0[i] = 0.f; acc1[i] = 0.f; by0[i] = 0.f; by1[i] = 0.f; }
  for (int ci = 0; ci < 8; ++ci) {
    wldI(Wff, Wb, oc0 + ci, wA);
    wldI(Wff, Wb, oc1 + ci, wC);
    conv16x2<true, false>(pb + (size_t)ci * 1024, wA, wC, 0.f,
                          strip4, cg4, cg0, cg7, acc0, acc1, by0, by1);
  }
  size_t off = (size_t)ciO * 524288 + (size_t)(b * 128 + och0) * 1024 + strip4 * 32 + cg4;
#pragma unroll
  for (int k = 0; k < 4; ++k) {
    *(float4*)(Q  + off + k * 32) = {acc0[k*4], acc0[k*4+1], acc0[k*4+2], acc0[k*4+3]};
    *(float4*)(Bq + off + k * 32) = {by0[k*4],  by0[k*4+1],  by0[k*4+2],  by0[k*4+3]};
    *(float4*)(Q  + off + 1024 + k * 32) = {acc1[k*4], acc1[k*4+1], acc1[k*4+2], acc1[k*4+3]};
    *(float4*)(Bq + off + 1024 + k * 32) = {by1[k*4],  by1[k*4+1],  by1[k*4+2],  by1[k*4+3]};
  }
}

// ---- k_ysum: Y = relu(sum8 Q); out-base = Y + sum8 Bq -----------------------
__global__ __launch_bounds__(256) void k_ysum(const float* __restrict__ Q,
                                              const float* __restrict__ Bq,
                                              float* __restrict__ Y,
                                              float* __restrict__ out) {
  size_t i = (size_t)(blockIdx.x * 256 + threadIdx.x) * 4;
  float4 qs = {0.f, 0.f, 0.f, 0.f}, bs = {0.f, 0.f, 0.f, 0.f};
#pragma unroll
  for (int q = 0; q < 8; ++q) {
    float4 a = *(const float4*)(Q + (size_t)q * 524288 + i);
    float4 c = *(const float4*)(Bq + (size_t)q * 524288 + i);
    qs.x += a.x; qs.y += a.y; qs.z += a.z; qs.w += a.w;
    bs.x += c.x; bs.y += c.y; bs.z += c.z; bs.w += c.w;
  }
  qs.x = qs.x > 0.f ? qs.x : 0.f; qs.y = qs.y > 0.f ? qs.y : 0.f;
  qs.z = qs.z > 0.f ? qs.z : 0.f; qs.w = qs.w > 0.f ? qs.w : 0.f;
  *(float4*)(Y + i) = qs;
  float4 ob = {qs.x + bs.x, qs.y + bs.y, qs.z + bs.z, qs.w + bs.w};
  *(float4*)(out + i) = ob;
}

// ---- k_forward_p: partial conv3x3(Y, Wfb^T) over 8-ci slice -----------------
// grid 512 = b(2b)|ochP(3b)|ciS(4b); 2 och/thread (och 0..63)
__global__ __launch_bounds__(256, 2) void k_forward_p(const float* __restrict__ Y,
                                                      const float* __restrict__ Wfb,
                                                      float* __restrict__ PA) {
  int tid = threadIdx.x, blk = blockIdx.x;
  int ciS = blk & 15, ochP = (blk >> 4) & 7, b = blk >> 7;
  int wv = __builtin_amdgcn_readfirstlane(tid >> 6);
  int och0 = ochP * 8 + wv * 2;               // 0..62
  int strip4 = ((tid >> 3) & 7) * 4;
  int cg4 = (tid & 7) * 4;
  bool cg0 = (tid & 7) == 0, cg7 = (tid & 7) == 7;
  const float* pb = Y + (size_t)(b * 128 + ciS * 8) * 1024;
  float wA[10], wC[10];
  float acc0[16], acc1[16], dummy[16];
#pragma unroll
  for (int i = 0; i < 16; ++i) { acc0[i] = 0.f; acc1[i] = 0.f; }
  for (int ci = 0; ci < 8; ++ci) {
    int ciY = ciS * 8 + ci;
    wldF(Wfb, ciY, och0, wA);
    wldF(Wfb, ciY, och0 + 1, wC);
    conv16x2<false, false>(pb + (size_t)ci * 1024, wA, wC, 0.f,
                           strip4, cg4, cg0, cg7, acc0, acc1, dummy, dummy);
  }
  size_t off = (size_t)ciS * 262144 + (size_t)(b * 64 + och0) * 1024 + strip4 * 32 + cg4;
#pragma unroll
  for (int k = 0; k < 4; ++k) {
    *(float4*)(PA + off + k * 32) = {acc0[k*4], acc0[k*4+1], acc0[k*4+2], acc0[k*4+3]};
    *(float4*)(PA + off + 1024 + k * 32) = {acc1[k*4], acc1[k*4+1], acc1[k*4+2], acc1[k*4+3]};
  }
}

// ---- k_vnorm: v0 = x - sum16(PA); Gam[blk] = block partial of ||v0||^2 ------
__global__ __launch_bounds__(256) void k_vnorm(const float* __restrict__ x,
                                               const float* __restrict__ PA,
                                               float* __restrict__ v0out,
                                               float* __restrict__ Gam) {
  __shared__ float ws[4];
  int tid = threadIdx.x;
  size_t i = (size_t)(blockIdx.x * 256 + tid) * 4;
  float4 s = {0.f, 0.f, 0.f, 0.f};
#pragma unroll
  for (int o = 0; o < 16; ++o) {
    float4 q = *(const float4*)(PA + (size_t)o * 262144 + i);
    s.x += q.x; s.y += q.y; s.z += q.z; s.w += q.w;
  }
  float4 xv = *(const float4*)(x + i);
  float4 v = {xv.x - s.x, xv.y - s.y, xv.z - s.z, xv.w - s.w};
  *(float4*)(v0out + i) = v;
  float g = v.x * v.x + v.y * v.y + v.z * v.z + v.w * v.w;
#pragma unroll
  for (int d = 32; d; d >>= 1) g += __shfl_down(g, d, 64);
  if ((tid & 63) == 0) ws[tid >> 6] = g;
  __syncthreads();
  if (tid == 0) Gam[blockIdx.x] = ws[0] + ws[1] + ws[2] + ws[3];
}

// ---- k_finalize_p: partial conv3x3(d0*v0, flip(Wfb)) over 8-ci octant -------
// grid 512 = b(2b)|coP(4b)|ciO(3b). Gam[256] reduced here. Writes Fp partials.
__global__ __launch_bounds__(256, 2) void k_finalize_p(const float* __restrict__ V,
                                                       const float* __restrict__ Gam,
                                                       const float* __restrict__ Wfb,
                                                       float* __restrict__ Fp) {
  __shared__ float ws[4];
  int tid = threadIdx.x, blk = blockIdx.x;
  int ciO = blk & 7, coP = (blk >> 3) & 15, b = blk >> 7;
  int wv = __builtin_amdgcn_readfirstlane(tid >> 6);
  int co0 = coP * 8 + wv * 2;                 // 0..126
  int strip4 = ((tid >> 3) & 7) * 4;
  int cg4 = (tid & 7) * 4;
  bool cg0 = (tid & 7) == 0, cg7 = (tid & 7) == 7;
  // reduce Gam[0..255] -> g00 (deterministic, no atomic, no pre-zero)
  float g = Gam[tid];
#pragma unroll
  for (int d = 32; d; d >>= 1) g += __shfl_down(g, d, 64);
  if ((tid & 63) == 0) ws[tid >> 6] = g;
  __syncthreads();
  float d0 = ((float)NUM_ITERS * LR_F) *
             __builtin_amdgcn_rsqf(ws[0] + ws[1] + ws[2] + ws[3]);
  const float* pb = V + (size_t)(b * 64 + ciO * 8) * 1024;
  float wA[10], wC[10];
  float acc0[16], acc1[16], dummy[16];
#pragma unroll
  for (int i = 0; i < 16; ++i) { acc0[i] = 0.f; acc1[i] = 0.f; }
  for (int ci = 0; ci < 8; ++ci) {
    int civ = ciO * 8 + ci;
    wldZ(Wfb, co0, civ, wA);
    wldZ(Wfb, co0 + 1, civ, wC);
    conv16x2<false, true>(pb + (size_t)ci * 1024, wA, wC, d0,
                          strip4, cg4, cg0, cg7, acc0, acc1, dummy, dummy);
  }
  size_t off = (size_t)ciO * 524288 + (size_t)(b * 128 + co0) * 1024 + strip4 * 32 + cg4;
#pragma unroll
  for (int k = 0; k < 4; ++k) {
    *(float4*)(Fp + off + k * 32) = {acc0[k*4], acc0[k*4+1], acc0[k*4+2], acc0[k*4+3]};
    *(float4*)(Fp + off + 1024 + k * 32) = {acc1[k*4], acc1[k*4+1], acc1[k*4+2], acc1[k*4+3]};
  }
}

// ---- k_fsum2: out += sum8 Fp (base written by k_ysum) -----------------------
__global__ __launch_bounds__(256) void k_fsum2(const float* __restrict__ Fp,
                                               float* __restrict__ out) {
  size_t i = (size_t)(blockIdx.x * 256 + threadIdx.x) * 4;
  float4 s = *(const float4*)(out + i);
#pragma unroll
  for (int q = 0; q < 8; ++q) {
    float4 p = *(const float4*)(Fp + (size_t)q * 524288 + i);
    s.x += p.x; s.y += p.y; s.z += p.z; s.w += p.w;
  }
  *(float4*)(out + i) = s;
}

// ---- launch -----------------------------------------------------------------
extern "C" void kernel_launch(void* const* d_in, const int* in_sizes, int n_in,
                              void* d_out, int out_size, void* d_ws, size_t ws_size,
                              hipStream_t stream) {
  const float* x   = (const float*)d_in[0];
  const float* Wff = (const float*)d_in[1];
  const float* Wfb = (const float*)d_in[2];
  const float* Wb  = (const float*)d_in[3];
  float* out = (float*)d_out;

  float* V    = (float*)d_ws;                  // 262144 (v0)
  float* Gam  = V + VPLANE;                    // 256 block partials
  float* PA   = Gam + 256;                     // 16 * 262144
  float* Q    = PA + (size_t)16 * 262144;      // 8 * 524288
  float* Bq   = Q + (size_t)8 * 524288;        // 8 * 524288
  float* Fp   = Bq + (size_t)8 * 524288;       // 8 * 524288
  float* Y    = Fp + (size_t)8 * 524288;       // 524288 (relu(sum Q))

  hipLaunchKernelGGL(k_init_p,     dim3(512), dim3(256), 0, stream, x, Wff, Wb, Q, Bq);
  hipLaunchKernelGGL(k_ysum,       dim3(512), dim3(256), 0, stream, Q, Bq, Y, out);
  hipLaunchKernelGGL(k_forward_p,  dim3(512), dim3(256), 0, stream, Y, Wfb, PA);
  hipLaunchKernelGGL(k_vnorm,      dim3(256), dim3(256), 0, stream, x, PA, V, Gam);
  hipLaunchKernelGGL(k_finalize_p, dim3(512), dim3(256), 0, stream, V, Gam, Wfb, Fp);
  hipLaunchKernelGGL(k_fsum2,      dim3(512), dim3(256), 0, stream, Fp, out);
}